// Round 5
// baseline (2650.988 us; speedup 1.0000x reference)
//
#include <hip/hip_runtime.h>
#include <math.h>

#define U_CNT 100000
#define I_CNT 50000
#define D_DIM 64
#define N_CNT 150000
#define B_CNT 8192
#define NEG_SLOPE 0.2f
#define REG_LAMBDA 1e-4f

#define RPB 128
#define NBK ((N_CNT + RPB - 1) / RPB)

__device__ __forceinline__ float bf2f(unsigned short u) {
    return __uint_as_float((unsigned int)u << 16);
}
__device__ __forceinline__ unsigned short f2bf(float f) {
    unsigned int x = __float_as_uint(f);
    x += 0x7FFFu + ((x >> 16) & 1u);   // RNE
    return (unsigned short)(x >> 16);
}

// ---------------- bf16 conversion of concat(uemb, iemb) -> [N][64] ----------------
__global__ __launch_bounds__(256) void k_cvt(const float* __restrict__ uemb,
                                             const float* __restrict__ iemb,
                                             unsigned short* __restrict__ dst) {
    long long i = (long long)blockIdx.x * 256 + threadIdx.x;
    long long base = i * 8;
    const long long TOT = (long long)N_CNT * 64;
    if (base >= TOT) return;
    const long long USZ = (long long)U_CNT * 64;
    const float* s = (base < USZ) ? uemb + base : iemb + (base - USZ);
    float4 a = *(const float4*)s;
    float4 b = *(const float4*)(s + 4);
    union { unsigned short us[8]; uint4 v; } o;
    o.us[0] = f2bf(a.x); o.us[1] = f2bf(a.y); o.us[2] = f2bf(a.z); o.us[3] = f2bf(a.w);
    o.us[4] = f2bf(b.x); o.us[5] = f2bf(b.y); o.us[6] = f2bf(b.z); o.us[7] = f2bf(b.w);
    *(uint4*)(dst + base) = o.v;
}

// ---------------- bucketed edge sort (bucket granularity only) ----------------

__global__ __launch_bounds__(256) void k_bhist(const int* __restrict__ rows,
                                               int* __restrict__ bcnt, int E) {
    __shared__ int h[NBK];
    for (int i = threadIdx.x; i < NBK; i += 256) h[i] = 0;
    __syncthreads();
    int per = (E + gridDim.x - 1) / gridDim.x;
    int s = blockIdx.x * per, e = min(E, s + per);
    for (int i = s + threadIdx.x; i < e; i += 256) atomicAdd(&h[rows[i] >> 7], 1);
    __syncthreads();
    for (int i = threadIdx.x; i < NBK; i += 256) {
        int v = h[i];
        if (v) atomicAdd(&bcnt[i], v);
    }
}

__global__ void k_bscan(const int* __restrict__ bcnt, int* __restrict__ bb, int n) {
    __shared__ int lds[256];
    __shared__ int base;
    int tid = threadIdx.x;
    if (tid == 0) { base = 0; bb[0] = 0; }
    __syncthreads();
    for (int start = 0; start < n; start += 256) {
        int i = start + tid;
        int x = (i < n) ? bcnt[i] : 0;
        lds[tid] = x;
        __syncthreads();
        for (int off = 1; off < 256; off <<= 1) {
            int t = (tid >= off) ? lds[tid - off] : 0;
            __syncthreads();
            lds[tid] += t;
            __syncthreads();
        }
        if (i < n) bb[i + 1] = base + lds[tid];
        __syncthreads();
        if (tid == 0) base += lds[255];
        __syncthreads();
    }
}

__global__ __launch_bounds__(256) void k_bscatterA(const int* __restrict__ rows,
                                                   const int* __restrict__ cols,
                                                   const float* __restrict__ vals,
                                                   const int* __restrict__ bb,
                                                   int* __restrict__ bfill,
                                                   int2* __restrict__ edges, int E) {
    __shared__ int h[NBK];
    __shared__ int f[NBK];
    for (int i = threadIdx.x; i < NBK; i += 256) { h[i] = 0; f[i] = 0; }
    __syncthreads();
    int per = (E + gridDim.x - 1) / gridDim.x;
    int s = blockIdx.x * per, e = min(E, s + per);
    for (int i = s + threadIdx.x; i < e; i += 256) atomicAdd(&h[rows[i] >> 7], 1);
    __syncthreads();
    for (int i = threadIdx.x; i < NBK; i += 256) {
        int c = h[i];
        h[i] = c ? atomicAdd(&bfill[i], c) : 0;
    }
    __syncthreads();
    for (int i = s + threadIdx.x; i < e; i += 256) {
        int r = rows[i];
        int b = r >> 7, rl = r & 127;
        int pos = atomicAdd(&f[b], 1);
        int slot = bb[b] + h[b] + pos;
        edges[slot] = make_int2((rl << 18) | cols[i], __float_as_int(vals[i]));
    }
}

// ---------------- SPMM: one block per bucket, LDS accumulate ----------------
__global__ __launch_bounds__(256) void k_spmm_b(const int2* __restrict__ edges,
                                                const int* __restrict__ bb,
                                                const unsigned short* __restrict__ src,
                                                unsigned short* __restrict__ out_bf) {
    __shared__ float accs[RPB * 64];  // 32 KB
    int b = blockIdx.x;
    int tid = threadIdx.x;
    {
        float4* a4 = (float4*)accs;
        for (int i = tid; i < RPB * 16; i += 256) a4[i] = make_float4(0.f, 0.f, 0.f, 0.f);
    }
    __syncthreads();

    int s = bb[b], e = bb[b + 1];
    int lane = tid & 63;
    int wv = tid >> 6;

    for (int base = s + (wv << 6); base < e; base += 256) {
        int idx = base + lane;
        int2 my = make_int2(0, 0);
        if (idx < e) my = edges[idx];
        int cnt = min(64, e - base);
        for (int j = 0; j < cnt; j += 8) {
            float av[8], evv[8];
            int rll[8];
#pragma unroll
            for (int t = 0; t < 8; ++t) {
                int jj = j + t;
                int pk = __shfl(my.x, jj);
                int pv = __shfl(my.y, jj);
                bool ok = (jj < cnt);
                pk = ok ? pk : 0;
                evv[t] = ok ? __int_as_float(pv) : 0.f;
                rll[t] = pk >> 18;
                int col = pk & 0x3FFFF;
                av[t] = bf2f(src[(size_t)col * 64 + lane]);
            }
#pragma unroll
            for (int t = 0; t < 8; ++t) {
                atomicAdd(&accs[rll[t] * 64 + lane], evv[t] * av[t]);
            }
        }
    }
    __syncthreads();

    // writeout: 4 dims per thread, bf16 packed, coalesced
    for (int q = tid; q < RPB * 16; q += 256) {
        int i = q * 4;
        int row = i >> 6;
        int gr = b * RPB + row;
        if (gr < N_CNT) {
            float4 v = *(float4*)&accs[i];
            union { unsigned short us[4]; uint2 u; } o;
            o.us[0] = f2bf(v.x); o.us[1] = f2bf(v.y);
            o.us[2] = f2bf(v.z); o.us[3] = f2bf(v.w);
            *(uint2*)&out_bf[(size_t)gr * 64 + (i & 63)] = o.u;
        }
    }
}

// ---------------- fused dense ----------------
template <int WRITE_BF>
__global__ __launch_bounds__(256, 1) void k_dense(const unsigned short* __restrict__ x_in,
                                                  const float* __restrict__ Wg,
                                                  const float* __restrict__ bg,
                                                  const float* __restrict__ Wm,
                                                  const float* __restrict__ bm,
                                                  float* __restrict__ out,
                                                  unsigned short* __restrict__ out_bf,
                                                  float* __restrict__ rnorm) {
    __shared__ __align__(16) float sWgT[4096];
    __shared__ __align__(16) float sWm[4096];
    __shared__ float sbg[64], sbm[64];
    int tid = threadIdx.x;
    for (int i = tid; i < 4096; i += 256) {
        int k = i >> 6, j = i & 63;
        sWgT[j * 64 + k] = Wg[i];
        sWm[i] = Wm[i];
    }
    if (tid < 64) {
        sbg[tid] = bg[tid];
        sbm[tid] = bm[tid];
    }
    __syncthreads();
    int r = blockIdx.x * 256 + tid;
    if (r >= N_CNT) return;

    float xr[64];
    const uint4* xp = (const uint4*)(x_in + (size_t)r * 64);
#pragma unroll
    for (int t = 0; t < 8; ++t) {
        uint4 q = xp[t];
        unsigned int u;
        u = q.x; xr[t * 8 + 0] = __uint_as_float(u << 16); xr[t * 8 + 1] = __uint_as_float(u & 0xFFFF0000u);
        u = q.y; xr[t * 8 + 2] = __uint_as_float(u << 16); xr[t * 8 + 3] = __uint_as_float(u & 0xFFFF0000u);
        u = q.z; xr[t * 8 + 4] = __uint_as_float(u << 16); xr[t * 8 + 5] = __uint_as_float(u & 0xFFFF0000u);
        u = q.w; xr[t * 8 + 6] = __uint_as_float(u << 16); xr[t * 8 + 7] = __uint_as_float(u & 0xFFFF0000u);
    }

    float z[64];
#pragma unroll
    for (int j = 0; j < 64; ++j) z[j] = sbm[j];

    for (int j = 0; j < 64; ++j) {
        float acc = sbg[j];
#pragma unroll
        for (int k = 0; k < 16; ++k) {
            float4 w = *(const float4*)&sWgT[j * 64 + k * 4];
            acc = fmaf(xr[k * 4 + 0], w.x, acc);
            acc = fmaf(xr[k * 4 + 1], w.y, acc);
            acc = fmaf(xr[k * 4 + 2], w.z, acc);
            acc = fmaf(xr[k * 4 + 3], w.w, acc);
        }
        float y = (acc >= 0.f) ? acc : NEG_SLOPE * acc;
#pragma unroll
        for (int k = 0; k < 16; ++k) {
            float4 w = *(const float4*)&sWm[j * 64 + k * 4];
            z[k * 4 + 0] = fmaf(y, w.x, z[k * 4 + 0]);
            z[k * 4 + 1] = fmaf(y, w.y, z[k * 4 + 1]);
            z[k * 4 + 2] = fmaf(y, w.z, z[k * 4 + 2]);
            z[k * 4 + 3] = fmaf(y, w.w, z[k * 4 + 3]);
        }
    }
    float nrm2 = 0.f;
#pragma unroll
    for (int j = 0; j < 64; ++j) nrm2 = fmaf(z[j], z[j], nrm2);
    float nrm = sqrtf(nrm2);
    float rn = 1.f / fmaxf(nrm, 1e-12f);
    rnorm[r] = rn;
    float4* op = (float4*)(out + (size_t)r * 64);
#pragma unroll
    for (int i = 0; i < 16; ++i) {
        float4 t;
        t.x = z[i * 4 + 0];
        t.y = z[i * 4 + 1];
        t.z = z[i * 4 + 2];
        t.w = z[i * 4 + 3];
        op[i] = t;
    }
    if (WRITE_BF) {
        uint4* bp = (uint4*)(out_bf + (size_t)r * 64);
#pragma unroll
        for (int t = 0; t < 8; ++t) {
            union { unsigned short us[8]; uint4 v; } o;
#pragma unroll
            for (int q = 0; q < 8; ++q) o.us[q] = f2bf(z[t * 8 + q]);
            bp[t] = o.v;
        }
    }
}

// ---------------- BPR scoring: grid-stride waves, 2 atomics/block ----------------
#define SCORE_BLOCKS 128
__global__ __launch_bounds__(256) void k_score(const int* __restrict__ user,
                                               const int* __restrict__ posi,
                                               const int* __restrict__ negi,
                                               const float* __restrict__ uemb,
                                               const float* __restrict__ iemb,
                                               const float* __restrict__ ego1,
                                               const float* __restrict__ rn1,
                                               const float* __restrict__ ego2,
                                               const float* __restrict__ rn2,
                                               float* __restrict__ out) {
    __shared__ float ssp[4], srg[4];
    int tid = threadIdx.x;
    int lane = tid & 63;
    int wv = tid >> 6;
    int gw = blockIdx.x * 4 + wv;
    const int NW = SCORE_BLOCKS * 4;

    float sp_acc = 0.f, rg_acc = 0.f;
    for (int w = gw; w < B_CNT; w += NW) {
        int iu = user[w], ip = posi[w], ineg = negi[w];
        size_t ru = (size_t)iu;
        size_t rp = (size_t)U_CNT + ip;
        size_t rn_ = (size_t)U_CNT + ineg;

        float u0 = uemb[(size_t)iu * 64 + lane];
        float p0 = iemb[(size_t)ip * 64 + lane];
        float n0 = iemb[(size_t)ineg * 64 + lane];
        float pos = u0 * p0;
        float neg = u0 * n0;
        float reg = u0 * u0 + p0 * p0 + n0 * n0;

        float a1 = rn1[ru], b1 = rn1[rp], c1 = rn1[rn_];
        float u1 = ego1[ru * 64 + lane] * a1;
        float p1 = ego1[rp * 64 + lane] * b1;
        float n1 = ego1[rn_ * 64 + lane] * c1;
        pos = fmaf(u1, p1, pos);
        neg = fmaf(u1, n1, neg);

        float a2 = rn2[ru], b2 = rn2[rp], c2 = rn2[rn_];
        float u2 = ego2[ru * 64 + lane] * a2;
        float p2 = ego2[rp * 64 + lane] * b2;
        float n2 = ego2[rn_ * 64 + lane] * c2;
        pos = fmaf(u2, p2, pos);
        neg = fmaf(u2, n2, neg);

#pragma unroll
        for (int off = 32; off; off >>= 1) {
            pos += __shfl_xor(pos, off);
            neg += __shfl_xor(neg, off);
            reg += __shfl_xor(reg, off);
        }
        float t = neg - pos;
        float sp = fmaxf(t, 0.f) + log1pf(expf(-fabsf(t)));
        sp_acc += sp;
        rg_acc += reg;
    }
    if (lane == 0) {
        ssp[wv] = sp_acc;
        srg[wv] = rg_acc;
    }
    __syncthreads();
    if (tid == 0) {
        float s = ssp[0] + ssp[1] + ssp[2] + ssp[3];
        float r = srg[0] + srg[1] + srg[2] + srg[3];
        atomicAdd(&out[0], s * (1.0f / B_CNT));
        atomicAdd(&out[1], r * (0.5f * REG_LAMBDA / B_CNT));
    }
}

// ---------------- launch ----------------

static inline size_t alignup(size_t x) { return (x + 255) & ~(size_t)255; }

extern "C" void kernel_launch(void* const* d_in, const int* in_sizes, int n_in,
                              void* d_out, int out_size, void* d_ws, size_t ws_size,
                              hipStream_t stream) {
    const int* user = (const int*)d_in[0];
    const int* posi = (const int*)d_in[1];
    const int* negi = (const int*)d_in[2];
    const int* rows = (const int*)d_in[3];
    const int* cols = (const int*)d_in[4];
    const float* vals = (const float*)d_in[5];
    const float* uemb = (const float*)d_in[6];
    const float* iemb = (const float*)d_in[7];
    const float* Wg0 = (const float*)d_in[8];
    const float* bg0 = (const float*)d_in[9];
    const float* Wm0 = (const float*)d_in[10];
    const float* bm0 = (const float*)d_in[11];
    const float* Wg1 = (const float*)d_in[12];
    const float* bg1 = (const float*)d_in[13];
    const float* Wm1 = (const float*)d_in[14];
    const float* bm1 = (const float*)d_in[15];
    const int E = in_sizes[3];
    float* out = (float*)d_out;

    char* p = (char*)d_ws;
    auto take = [&](size_t bytes) -> char* {
        char* q = p;
        p += alignup(bytes);
        return q;
    };
    int* bcnt = (int*)take((size_t)NBK * 4 * 2);
    int* bfill = bcnt + NBK;
    int* bb = (int*)take((size_t)(NBK + 1) * 4);
    int2* edges = (int2*)take((size_t)E * 8);
    unsigned short* ego0_bf = (unsigned short*)take((size_t)N_CNT * 64 * 2);
    unsigned short* side_bf = (unsigned short*)take((size_t)N_CNT * 64 * 2);
    unsigned short* ego1_bf = (unsigned short*)take((size_t)N_CNT * 64 * 2);
    float* ego1 = (float*)take((size_t)N_CNT * 64 * 4);
    float* ego2 = (float*)take((size_t)N_CNT * 64 * 4);
    float* rn1 = (float*)take((size_t)N_CNT * 4);
    float* rn2 = (float*)take((size_t)N_CNT * 4);

    hipMemsetAsync(out, 0, 2 * sizeof(float), stream);
    hipMemsetAsync(bcnt, 0, (size_t)NBK * 4 * 2, stream);

    const long long TOT = (long long)N_CNT * 64;
    int cb = (int)((TOT / 8 + 255) / 256);
    k_cvt<<<cb, 256, 0, stream>>>(uemb, iemb, ego0_bf);

    k_bhist<<<256, 256, 0, stream>>>(rows, bcnt, E);
    k_bscan<<<1, 256, 0, stream>>>(bcnt, bb, NBK);
    k_bscatterA<<<256, 256, 0, stream>>>(rows, cols, vals, bb, bfill, edges, E);

    int db = (N_CNT + 255) / 256;

    k_spmm_b<<<NBK, 256, 0, stream>>>(edges, bb, ego0_bf, side_bf);
    k_dense<1><<<db, 256, 0, stream>>>(side_bf, Wg0, bg0, Wm0, bm0, ego1, ego1_bf, rn1);
    k_spmm_b<<<NBK, 256, 0, stream>>>(edges, bb, ego1_bf, side_bf);
    k_dense<0><<<db, 256, 0, stream>>>(side_bf, Wg1, bg1, Wm1, bm1, ego2, (unsigned short*)nullptr, rn2);

    k_score<<<SCORE_BLOCKS, 256, 0, stream>>>(user, posi, negi, uemb, iemb,
                                              ego1, rn1, ego2, rn2, out);
}

// Round 6
// 675.396 us; speedup vs baseline: 3.9251x; 3.9251x over previous
//
#include <hip/hip_runtime.h>
#include <math.h>

#define U_CNT 100000
#define I_CNT 50000
#define D_DIM 64
#define N_CNT 150000
#define B_CNT 8192
#define NEG_SLOPE 0.2f
#define REG_LAMBDA 1e-4f

#define RPB 128
#define NBK ((N_CNT + RPB - 1) / RPB)
#define CAP 4096

__device__ __forceinline__ float bf2f(unsigned short u) {
    return __uint_as_float((unsigned int)u << 16);
}
__device__ __forceinline__ unsigned short f2bf(float f) {
    unsigned int x = __float_as_uint(f);
    x += 0x7FFFu + ((x >> 16) & 1u);   // RNE
    return (unsigned short)(x >> 16);
}

// ---------------- bf16 conversion of concat(uemb, iemb) -> [N][64] ----------------
__global__ __launch_bounds__(256) void k_cvt(const float* __restrict__ uemb,
                                             const float* __restrict__ iemb,
                                             unsigned short* __restrict__ dst) {
    long long i = (long long)blockIdx.x * 256 + threadIdx.x;
    long long base = i * 8;
    const long long TOT = (long long)N_CNT * 64;
    if (base >= TOT) return;
    const long long USZ = (long long)U_CNT * 64;
    const float* s = (base < USZ) ? uemb + base : iemb + (base - USZ);
    float4 a = *(const float4*)s;
    float4 b = *(const float4*)(s + 4);
    union { unsigned short us[8]; uint4 v; } o;
    o.us[0] = f2bf(a.x); o.us[1] = f2bf(a.y); o.us[2] = f2bf(a.z); o.us[3] = f2bf(a.w);
    o.us[4] = f2bf(b.x); o.us[5] = f2bf(b.y); o.us[6] = f2bf(b.z); o.us[7] = f2bf(b.w);
    *(uint4*)(dst + base) = o.v;
}

// ---------------- bucketed CSR build ----------------

__global__ __launch_bounds__(256) void k_bhist(const int* __restrict__ rows,
                                               int* __restrict__ bcnt, int E) {
    __shared__ int h[NBK];
    for (int i = threadIdx.x; i < NBK; i += 256) h[i] = 0;
    __syncthreads();
    int per = (E + gridDim.x - 1) / gridDim.x;
    int s = blockIdx.x * per, e = min(E, s + per);
    for (int i = s + threadIdx.x; i < e; i += 256) atomicAdd(&h[rows[i] >> 7], 1);
    __syncthreads();
    for (int i = threadIdx.x; i < NBK; i += 256) {
        int v = h[i];
        if (v) atomicAdd(&bcnt[i], v);
    }
}

__global__ void k_bscan(const int* __restrict__ bcnt, int* __restrict__ bb, int n) {
    __shared__ int lds[256];
    __shared__ int base;
    int tid = threadIdx.x;
    if (tid == 0) { base = 0; bb[0] = 0; }
    __syncthreads();
    for (int start = 0; start < n; start += 256) {
        int i = start + tid;
        int x = (i < n) ? bcnt[i] : 0;
        lds[tid] = x;
        __syncthreads();
        for (int off = 1; off < 256; off <<= 1) {
            int t = (tid >= off) ? lds[tid - off] : 0;
            __syncthreads();
            lds[tid] += t;
            __syncthreads();
        }
        if (i < n) bb[i + 1] = base + lds[tid];
        __syncthreads();
        if (tid == 0) base += lds[255];
        __syncthreads();
    }
}

__global__ __launch_bounds__(256) void k_bscatterA(const int* __restrict__ rows,
                                                   const int* __restrict__ cols,
                                                   const float* __restrict__ vals,
                                                   const int* __restrict__ bb,
                                                   int* __restrict__ bfill,
                                                   int2* __restrict__ edges, int E) {
    __shared__ int h[NBK];
    __shared__ int f[NBK];
    for (int i = threadIdx.x; i < NBK; i += 256) { h[i] = 0; f[i] = 0; }
    __syncthreads();
    int per = (E + gridDim.x - 1) / gridDim.x;
    int s = blockIdx.x * per, e = min(E, s + per);
    for (int i = s + threadIdx.x; i < e; i += 256) atomicAdd(&h[rows[i] >> 7], 1);
    __syncthreads();
    for (int i = threadIdx.x; i < NBK; i += 256) {
        int c = h[i];
        h[i] = c ? atomicAdd(&bfill[i], c) : 0;
    }
    __syncthreads();
    for (int i = s + threadIdx.x; i < e; i += 256) {
        int r = rows[i];
        int b = r >> 7, rl = r & 127;
        int pos = atomicAdd(&f[b], 1);
        int slot = bb[b] + h[b] + pos;
        edges[slot] = make_int2((rl << 18) | cols[i], __float_as_int(vals[i]));
    }
}

__global__ __launch_bounds__(256) void k_bfinal(int2* __restrict__ edges,
                                                const int* __restrict__ bb,
                                                int* __restrict__ rs, int E) {
    __shared__ int2 led[CAP];
    __shared__ int lcnt[RPB], lscan[RPB], lfill[RPB];
    int b = blockIdx.x;
    int s = bb[b], e = bb[b + 1];
    int nb = e - s;
    int tid = threadIdx.x;
    if (tid < RPB) { lcnt[tid] = 0; lfill[tid] = 0; }
    __syncthreads();
    for (int i = tid; i < nb; i += 256) {
        int2 ed = edges[s + i];
        if (i < CAP) led[i] = ed;
        atomicAdd(&lcnt[ed.x >> 18], 1);
    }
    __syncthreads();
    if (tid == 0) {
        int run = 0;
        for (int j = 0; j < RPB; ++j) { lscan[j] = run; run += lcnt[j]; }
    }
    __syncthreads();
    if (tid < RPB) {
        int row = b * RPB + tid;
        if (row < N_CNT) rs[row] = s + lscan[tid];
    }
    if (b == gridDim.x - 1 && tid == 0) rs[N_CNT] = E;
    int lim = min(nb, CAP);
    for (int i = tid; i < lim; i += 256) {
        int2 ed = led[i];
        int rl = ed.x >> 18;
        int pos = atomicAdd(&lfill[rl], 1);
        edges[s + lscan[rl] + pos] = make_int2(ed.x & 0x3FFFF, ed.y);
    }
    for (int base = CAP; base < nb; base += 256) {
        int i = base + tid;
        int2 ed;
        bool ok = (i < nb);
        if (ok) ed = edges[s + i];
        __syncthreads();
        if (ok) {
            int rl = ed.x >> 18;
            int pos = atomicAdd(&lfill[rl], 1);
            edges[s + lscan[rl] + pos] = make_int2(ed.x & 0x3FFFF, ed.y);
        }
        __syncthreads();
    }
}

// ---------------- SPMM: wave-per-row, depth-8 software pipeline ----------------
__global__ __launch_bounds__(256) void k_spmm(const int* __restrict__ rs,
                                              const int2* __restrict__ edges,
                                              const unsigned short* __restrict__ src,
                                              unsigned short* __restrict__ out_bf) {
    int gid = blockIdx.x * blockDim.x + threadIdx.x;
    int w = gid >> 6;
    int lane = gid & 63;
    if (w >= N_CNT) return;
    int s = rs[w], e = rs[w + 1];
    float acc0 = 0.f, acc1 = 0.f;

    int2 b[8];
#pragma unroll
    for (int t = 0; t < 8; ++t) {
        int idx = s + t;
        b[t] = (idx < e) ? edges[idx] : make_int2(0, 0);
    }
    for (int base = s; base < e; base += 8) {
        int2 nx[8];
#pragma unroll
        for (int t = 0; t < 8; ++t) {
            int idx = base + 8 + t;
            nx[t] = (idx < e) ? edges[idx] : make_int2(0, 0);
        }
        float a[8];
#pragma unroll
        for (int t = 0; t < 8; ++t) {
            a[t] = bf2f(src[(size_t)b[t].x * 64 + lane]);
        }
#pragma unroll
        for (int t = 0; t < 8; ++t) {
            float v = __int_as_float(b[t].y);
            if (t & 1) acc1 = fmaf(v, a[t], acc1);
            else       acc0 = fmaf(v, a[t], acc0);
        }
#pragma unroll
        for (int t = 0; t < 8; ++t) b[t] = nx[t];
    }
    out_bf[(size_t)w * 64 + lane] = f2bf(acc0 + acc1);
}

// ---------------- fused dense ----------------
template <int WRITE_BF>
__global__ __launch_bounds__(256, 1) void k_dense(const unsigned short* __restrict__ x_in,
                                                  const float* __restrict__ Wg,
                                                  const float* __restrict__ bg,
                                                  const float* __restrict__ Wm,
                                                  const float* __restrict__ bm,
                                                  float* __restrict__ out,
                                                  unsigned short* __restrict__ out_bf,
                                                  float* __restrict__ rnorm) {
    __shared__ __align__(16) float sWgT[4096];
    __shared__ __align__(16) float sWm[4096];
    __shared__ float sbg[64], sbm[64];
    int tid = threadIdx.x;
    for (int i = tid; i < 4096; i += 256) {
        int k = i >> 6, j = i & 63;
        sWgT[j * 64 + k] = Wg[i];
        sWm[i] = Wm[i];
    }
    if (tid < 64) {
        sbg[tid] = bg[tid];
        sbm[tid] = bm[tid];
    }
    __syncthreads();
    int r = blockIdx.x * 256 + tid;
    if (r >= N_CNT) return;

    float xr[64];
    const uint4* xp = (const uint4*)(x_in + (size_t)r * 64);
#pragma unroll
    for (int t = 0; t < 8; ++t) {
        uint4 q = xp[t];
        unsigned int u;
        u = q.x; xr[t * 8 + 0] = __uint_as_float(u << 16); xr[t * 8 + 1] = __uint_as_float(u & 0xFFFF0000u);
        u = q.y; xr[t * 8 + 2] = __uint_as_float(u << 16); xr[t * 8 + 3] = __uint_as_float(u & 0xFFFF0000u);
        u = q.z; xr[t * 8 + 4] = __uint_as_float(u << 16); xr[t * 8 + 5] = __uint_as_float(u & 0xFFFF0000u);
        u = q.w; xr[t * 8 + 6] = __uint_as_float(u << 16); xr[t * 8 + 7] = __uint_as_float(u & 0xFFFF0000u);
    }

    float z[64];
#pragma unroll
    for (int j = 0; j < 64; ++j) z[j] = sbm[j];

    for (int j = 0; j < 64; ++j) {
        float acc = sbg[j];
#pragma unroll
        for (int k = 0; k < 16; ++k) {
            float4 w = *(const float4*)&sWgT[j * 64 + k * 4];
            acc = fmaf(xr[k * 4 + 0], w.x, acc);
            acc = fmaf(xr[k * 4 + 1], w.y, acc);
            acc = fmaf(xr[k * 4 + 2], w.z, acc);
            acc = fmaf(xr[k * 4 + 3], w.w, acc);
        }
        float y = (acc >= 0.f) ? acc : NEG_SLOPE * acc;
#pragma unroll
        for (int k = 0; k < 16; ++k) {
            float4 w = *(const float4*)&sWm[j * 64 + k * 4];
            z[k * 4 + 0] = fmaf(y, w.x, z[k * 4 + 0]);
            z[k * 4 + 1] = fmaf(y, w.y, z[k * 4 + 1]);
            z[k * 4 + 2] = fmaf(y, w.z, z[k * 4 + 2]);
            z[k * 4 + 3] = fmaf(y, w.w, z[k * 4 + 3]);
        }
    }
    float nrm2 = 0.f;
#pragma unroll
    for (int j = 0; j < 64; ++j) nrm2 = fmaf(z[j], z[j], nrm2);
    float nrm = sqrtf(nrm2);
    float rn = 1.f / fmaxf(nrm, 1e-12f);
    rnorm[r] = rn;
    float4* op = (float4*)(out + (size_t)r * 64);
#pragma unroll
    for (int i = 0; i < 16; ++i) {
        float4 t;
        t.x = z[i * 4 + 0];
        t.y = z[i * 4 + 1];
        t.z = z[i * 4 + 2];
        t.w = z[i * 4 + 3];
        op[i] = t;
    }
    if (WRITE_BF) {
        uint4* bp = (uint4*)(out_bf + (size_t)r * 64);
#pragma unroll
        for (int t = 0; t < 8; ++t) {
            union { unsigned short us[8]; uint4 v; } o;
#pragma unroll
            for (int q = 0; q < 8; ++q) o.us[q] = f2bf(z[t * 8 + q]);
            bp[t] = o.v;
        }
    }
}

// ---------------- BPR scoring: grid-stride waves, 2 atomics/block ----------------
#define SCORE_BLOCKS 128
__global__ __launch_bounds__(256) void k_score(const int* __restrict__ user,
                                               const int* __restrict__ posi,
                                               const int* __restrict__ negi,
                                               const float* __restrict__ uemb,
                                               const float* __restrict__ iemb,
                                               const float* __restrict__ ego1,
                                               const float* __restrict__ rn1,
                                               const float* __restrict__ ego2,
                                               const float* __restrict__ rn2,
                                               float* __restrict__ out) {
    __shared__ float ssp[4], srg[4];
    int tid = threadIdx.x;
    int lane = tid & 63;
    int wv = tid >> 6;
    int gw = blockIdx.x * 4 + wv;
    const int NW = SCORE_BLOCKS * 4;

    float sp_acc = 0.f, rg_acc = 0.f;
    for (int w = gw; w < B_CNT; w += NW) {
        int iu = user[w], ip = posi[w], ineg = negi[w];
        size_t ru = (size_t)iu;
        size_t rp = (size_t)U_CNT + ip;
        size_t rn_ = (size_t)U_CNT + ineg;

        float u0 = uemb[(size_t)iu * 64 + lane];
        float p0 = iemb[(size_t)ip * 64 + lane];
        float n0 = iemb[(size_t)ineg * 64 + lane];
        float pos = u0 * p0;
        float neg = u0 * n0;
        float reg = u0 * u0 + p0 * p0 + n0 * n0;

        float a1 = rn1[ru], b1 = rn1[rp], c1 = rn1[rn_];
        float u1 = ego1[ru * 64 + lane] * a1;
        float p1 = ego1[rp * 64 + lane] * b1;
        float n1 = ego1[rn_ * 64 + lane] * c1;
        pos = fmaf(u1, p1, pos);
        neg = fmaf(u1, n1, neg);

        float a2 = rn2[ru], b2 = rn2[rp], c2 = rn2[rn_];
        float u2 = ego2[ru * 64 + lane] * a2;
        float p2 = ego2[rp * 64 + lane] * b2;
        float n2 = ego2[rn_ * 64 + lane] * c2;
        pos = fmaf(u2, p2, pos);
        neg = fmaf(u2, n2, neg);

#pragma unroll
        for (int off = 32; off; off >>= 1) {
            pos += __shfl_xor(pos, off);
            neg += __shfl_xor(neg, off);
            reg += __shfl_xor(reg, off);
        }
        float t = neg - pos;
        float sp = fmaxf(t, 0.f) + log1pf(expf(-fabsf(t)));
        sp_acc += sp;
        rg_acc += reg;
    }
    if (lane == 0) {
        ssp[wv] = sp_acc;
        srg[wv] = rg_acc;
    }
    __syncthreads();
    if (tid == 0) {
        float s = ssp[0] + ssp[1] + ssp[2] + ssp[3];
        float r = srg[0] + srg[1] + srg[2] + srg[3];
        atomicAdd(&out[0], s * (1.0f / B_CNT));
        atomicAdd(&out[1], r * (0.5f * REG_LAMBDA / B_CNT));
    }
}

// ---------------- launch ----------------

static inline size_t alignup(size_t x) { return (x + 255) & ~(size_t)255; }

extern "C" void kernel_launch(void* const* d_in, const int* in_sizes, int n_in,
                              void* d_out, int out_size, void* d_ws, size_t ws_size,
                              hipStream_t stream) {
    const int* user = (const int*)d_in[0];
    const int* posi = (const int*)d_in[1];
    const int* negi = (const int*)d_in[2];
    const int* rows = (const int*)d_in[3];
    const int* cols = (const int*)d_in[4];
    const float* vals = (const float*)d_in[5];
    const float* uemb = (const float*)d_in[6];
    const float* iemb = (const float*)d_in[7];
    const float* Wg0 = (const float*)d_in[8];
    const float* bg0 = (const float*)d_in[9];
    const float* Wm0 = (const float*)d_in[10];
    const float* bm0 = (const float*)d_in[11];
    const float* Wg1 = (const float*)d_in[12];
    const float* bg1 = (const float*)d_in[13];
    const float* Wm1 = (const float*)d_in[14];
    const float* bm1 = (const float*)d_in[15];
    const int E = in_sizes[3];
    float* out = (float*)d_out;

    char* p = (char*)d_ws;
    auto take = [&](size_t bytes) -> char* {
        char* q = p;
        p += alignup(bytes);
        return q;
    };
    int* rs = (int*)take((size_t)(N_CNT + 1) * 4);
    int* bcnt = (int*)take((size_t)NBK * 4 * 2);
    int* bfill = bcnt + NBK;
    int* bb = (int*)take((size_t)(NBK + 1) * 4);
    int2* edges = (int2*)take((size_t)E * 8);
    unsigned short* ego0_bf = (unsigned short*)take((size_t)N_CNT * 64 * 2);
    unsigned short* side_bf = (unsigned short*)take((size_t)N_CNT * 64 * 2);
    unsigned short* ego1_bf = (unsigned short*)take((size_t)N_CNT * 64 * 2);
    float* ego1 = (float*)take((size_t)N_CNT * 64 * 4);
    float* ego2 = (float*)take((size_t)N_CNT * 64 * 4);
    float* rn1 = (float*)take((size_t)N_CNT * 4);
    float* rn2 = (float*)take((size_t)N_CNT * 4);

    hipMemsetAsync(out, 0, 2 * sizeof(float), stream);
    hipMemsetAsync(bcnt, 0, (size_t)NBK * 4 * 2, stream);

    const long long TOT = (long long)N_CNT * 64;
    int cb = (int)((TOT / 8 + 255) / 256);
    k_cvt<<<cb, 256, 0, stream>>>(uemb, iemb, ego0_bf);

    k_bhist<<<256, 256, 0, stream>>>(rows, bcnt, E);
    k_bscan<<<1, 256, 0, stream>>>(bcnt, bb, NBK);
    k_bscatterA<<<256, 256, 0, stream>>>(rows, cols, vals, bb, bfill, edges, E);
    k_bfinal<<<NBK, 256, 0, stream>>>(edges, bb, rs, E);

    int sb = (N_CNT * 64 + 255) / 256;
    int db = (N_CNT + 255) / 256;

    k_spmm<<<sb, 256, 0, stream>>>(rs, edges, ego0_bf, side_bf);
    k_dense<1><<<db, 256, 0, stream>>>(side_bf, Wg0, bg0, Wm0, bm0, ego1, ego1_bf, rn1);
    k_spmm<<<sb, 256, 0, stream>>>(rs, edges, ego1_bf, side_bf);
    k_dense<0><<<db, 256, 0, stream>>>(side_bf, Wg1, bg1, Wm1, bm1, ego2, (unsigned short*)nullptr, rn2);

    k_score<<<SCORE_BLOCKS, 256, 0, stream>>>(user, posi, negi, uemb, iemb,
                                              ego1, rn1, ego2, rn2, out);
}

// Round 7
// 615.399 us; speedup vs baseline: 4.3078x; 1.0975x over previous
//
#include <hip/hip_runtime.h>
#include <math.h>

#define U_CNT 100000
#define I_CNT 50000
#define D_DIM 64
#define N_CNT 150000
#define B_CNT 8192
#define NEG_SLOPE 0.2f
#define REG_LAMBDA 1e-4f

#define RPB 128
#define NBK ((N_CNT + RPB - 1) / RPB)
#define CAP 4096

__device__ __forceinline__ float bf2f(unsigned short u) {
    return __uint_as_float((unsigned int)u << 16);
}
__device__ __forceinline__ unsigned short f2bf(float f) {
    unsigned int x = __float_as_uint(f);
    x += 0x7FFFu + ((x >> 16) & 1u);   // RNE
    return (unsigned short)(x >> 16);
}

// ---------------- bf16 conversion of concat(uemb, iemb) -> [N][64] ----------------
__global__ __launch_bounds__(256) void k_cvt(const float* __restrict__ uemb,
                                             const float* __restrict__ iemb,
                                             unsigned short* __restrict__ dst) {
    long long i = (long long)blockIdx.x * 256 + threadIdx.x;
    long long base = i * 8;
    const long long TOT = (long long)N_CNT * 64;
    if (base >= TOT) return;
    const long long USZ = (long long)U_CNT * 64;
    const float* s = (base < USZ) ? uemb + base : iemb + (base - USZ);
    float4 a = *(const float4*)s;
    float4 b = *(const float4*)(s + 4);
    union { unsigned short us[8]; uint4 v; } o;
    o.us[0] = f2bf(a.x); o.us[1] = f2bf(a.y); o.us[2] = f2bf(a.z); o.us[3] = f2bf(a.w);
    o.us[4] = f2bf(b.x); o.us[5] = f2bf(b.y); o.us[6] = f2bf(b.z); o.us[7] = f2bf(b.w);
    *(uint4*)(dst + base) = o.v;
}

// ---------------- bucketed CSR build ----------------

__global__ __launch_bounds__(256) void k_bhist(const int* __restrict__ rows,
                                               int* __restrict__ bcnt, int E) {
    __shared__ int h[NBK];
    for (int i = threadIdx.x; i < NBK; i += 256) h[i] = 0;
    __syncthreads();
    int per = (E + gridDim.x - 1) / gridDim.x;
    int s = blockIdx.x * per, e = min(E, s + per);
    for (int i = s + threadIdx.x; i < e; i += 256) atomicAdd(&h[rows[i] >> 7], 1);
    __syncthreads();
    for (int i = threadIdx.x; i < NBK; i += 256) {
        int v = h[i];
        if (v) atomicAdd(&bcnt[i], v);
    }
}

__global__ void k_bscan(const int* __restrict__ bcnt, int* __restrict__ bb, int n) {
    __shared__ int lds[256];
    __shared__ int base;
    int tid = threadIdx.x;
    if (tid == 0) { base = 0; bb[0] = 0; }
    __syncthreads();
    for (int start = 0; start < n; start += 256) {
        int i = start + tid;
        int x = (i < n) ? bcnt[i] : 0;
        lds[tid] = x;
        __syncthreads();
        for (int off = 1; off < 256; off <<= 1) {
            int t = (tid >= off) ? lds[tid - off] : 0;
            __syncthreads();
            lds[tid] += t;
            __syncthreads();
        }
        if (i < n) bb[i + 1] = base + lds[tid];
        __syncthreads();
        if (tid == 0) base += lds[255];
        __syncthreads();
    }
}

__global__ __launch_bounds__(256) void k_bscatterA(const int* __restrict__ rows,
                                                   const int* __restrict__ cols,
                                                   const float* __restrict__ vals,
                                                   const int* __restrict__ bb,
                                                   int* __restrict__ bfill,
                                                   int2* __restrict__ edges, int E) {
    __shared__ int h[NBK];
    __shared__ int f[NBK];
    for (int i = threadIdx.x; i < NBK; i += 256) { h[i] = 0; f[i] = 0; }
    __syncthreads();
    int per = (E + gridDim.x - 1) / gridDim.x;
    int s = blockIdx.x * per, e = min(E, s + per);
    for (int i = s + threadIdx.x; i < e; i += 256) atomicAdd(&h[rows[i] >> 7], 1);
    __syncthreads();
    for (int i = threadIdx.x; i < NBK; i += 256) {
        int c = h[i];
        h[i] = c ? atomicAdd(&bfill[i], c) : 0;
    }
    __syncthreads();
    for (int i = s + threadIdx.x; i < e; i += 256) {
        int r = rows[i];
        int b = r >> 7, rl = r & 127;
        int pos = atomicAdd(&f[b], 1);
        int slot = bb[b] + h[b] + pos;
        edges[slot] = make_int2((rl << 18) | cols[i], __float_as_int(vals[i]));
    }
}

__global__ __launch_bounds__(256) void k_bfinal(int2* __restrict__ edges,
                                                const int* __restrict__ bb,
                                                int* __restrict__ rs, int E) {
    __shared__ int2 led[CAP];
    __shared__ int lcnt[RPB], lscan[RPB], lfill[RPB];
    int b = blockIdx.x;
    int s = bb[b], e = bb[b + 1];
    int nb = e - s;
    int tid = threadIdx.x;
    if (tid < RPB) { lcnt[tid] = 0; lfill[tid] = 0; }
    __syncthreads();
    for (int i = tid; i < nb; i += 256) {
        int2 ed = edges[s + i];
        if (i < CAP) led[i] = ed;
        atomicAdd(&lcnt[ed.x >> 18], 1);
    }
    __syncthreads();
    if (tid == 0) {
        int run = 0;
        for (int j = 0; j < RPB; ++j) { lscan[j] = run; run += lcnt[j]; }
    }
    __syncthreads();
    if (tid < RPB) {
        int row = b * RPB + tid;
        if (row < N_CNT) rs[row] = s + lscan[tid];
    }
    if (b == gridDim.x - 1 && tid == 0) rs[N_CNT] = E;
    int lim = min(nb, CAP);
    for (int i = tid; i < lim; i += 256) {
        int2 ed = led[i];
        int rl = ed.x >> 18;
        int pos = atomicAdd(&lfill[rl], 1);
        edges[s + lscan[rl] + pos] = make_int2(ed.x & 0x3FFFF, ed.y);
    }
    for (int base = CAP; base < nb; base += 256) {
        int i = base + tid;
        int2 ed;
        bool ok = (i < nb);
        if (ok) ed = edges[s + i];
        __syncthreads();
        if (ok) {
            int rl = ed.x >> 18;
            int pos = atomicAdd(&lfill[rl], 1);
            edges[s + lscan[rl] + pos] = make_int2(ed.x & 0x3FFFF, ed.y);
        }
        __syncthreads();
    }
}

// ---------------- SPMM: wave-per-row, 4x16 quad-split lanes ----------------
// sub-group g (lanes 16g..16g+15) handles edge base+g; lane sl owns dims 4sl..4sl+3.
__global__ __launch_bounds__(256) void k_spmm(const int* __restrict__ rs,
                                              const int2* __restrict__ edges,
                                              const unsigned short* __restrict__ src,
                                              unsigned short* __restrict__ out_bf) {
    int gid = blockIdx.x * blockDim.x + threadIdx.x;
    int w = gid >> 6;
    if (w >= N_CNT) return;
    int lane = threadIdx.x & 63;
    int sub = lane >> 4;
    int sl = lane & 15;
    int s = rs[w], e = rs[w + 1];

    float a0 = 0.f, a1 = 0.f, a2 = 0.f, a3 = 0.f;

    int idx = s + sub;
    int2 cur = (idx < e) ? edges[idx] : make_int2(0, 0);
    if (idx >= e) cur.y = 0;
    for (int base = s; base < e; base += 4) {
        int nidx = base + 4 + sub;
        int2 nxt = make_int2(0, 0);
        if (nidx < e) nxt = edges[nidx];
        // gather 4 bf16 dims of this edge's source row
        unsigned int col = (unsigned int)cur.x;
        uint2 g = *(const uint2*)(src + (size_t)col * 64 + sl * 4);
        float v = __int_as_float(cur.y);
        a0 = fmaf(v, __uint_as_float(g.x << 16), a0);
        a1 = fmaf(v, __uint_as_float(g.x & 0xFFFF0000u), a1);
        a2 = fmaf(v, __uint_as_float(g.y << 16), a2);
        a3 = fmaf(v, __uint_as_float(g.y & 0xFFFF0000u), a3);
        cur = nxt;
    }
    // reduce across the 4 sub-groups
    a0 += __shfl_xor(a0, 16); a0 += __shfl_xor(a0, 32);
    a1 += __shfl_xor(a1, 16); a1 += __shfl_xor(a1, 32);
    a2 += __shfl_xor(a2, 16); a2 += __shfl_xor(a2, 32);
    a3 += __shfl_xor(a3, 16); a3 += __shfl_xor(a3, 32);
    if (sub == 0) {
        union { unsigned short us[4]; uint2 u; } o;
        o.us[0] = f2bf(a0); o.us[1] = f2bf(a1);
        o.us[2] = f2bf(a2); o.us[3] = f2bf(a3);
        *(uint2*)&out_bf[(size_t)w * 64 + sl * 4] = o.u;
    }
}

// ---------------- fused dense ----------------
template <int WRITE_BF>
__global__ __launch_bounds__(256, 2) void k_dense(const unsigned short* __restrict__ x_in,
                                                  const float* __restrict__ Wg,
                                                  const float* __restrict__ bg,
                                                  const float* __restrict__ Wm,
                                                  const float* __restrict__ bm,
                                                  float* __restrict__ out,
                                                  unsigned short* __restrict__ out_bf,
                                                  float* __restrict__ rnorm) {
    __shared__ __align__(16) float sWgT[4096];
    __shared__ __align__(16) float sWm[4096];
    __shared__ float sbg[64], sbm[64];
    int tid = threadIdx.x;
    for (int i = tid; i < 4096; i += 256) {
        int k = i >> 6, j = i & 63;
        sWgT[j * 64 + k] = Wg[i];
        sWm[i] = Wm[i];
    }
    if (tid < 64) {
        sbg[tid] = bg[tid];
        sbm[tid] = bm[tid];
    }
    __syncthreads();
    int r = blockIdx.x * 256 + tid;
    if (r >= N_CNT) return;

    float xr[64];
    const uint4* xp = (const uint4*)(x_in + (size_t)r * 64);
#pragma unroll
    for (int t = 0; t < 8; ++t) {
        uint4 q = xp[t];
        unsigned int u;
        u = q.x; xr[t * 8 + 0] = __uint_as_float(u << 16); xr[t * 8 + 1] = __uint_as_float(u & 0xFFFF0000u);
        u = q.y; xr[t * 8 + 2] = __uint_as_float(u << 16); xr[t * 8 + 3] = __uint_as_float(u & 0xFFFF0000u);
        u = q.z; xr[t * 8 + 4] = __uint_as_float(u << 16); xr[t * 8 + 5] = __uint_as_float(u & 0xFFFF0000u);
        u = q.w; xr[t * 8 + 6] = __uint_as_float(u << 16); xr[t * 8 + 7] = __uint_as_float(u & 0xFFFF0000u);
    }

    float z[64];
#pragma unroll
    for (int j = 0; j < 64; ++j) z[j] = sbm[j];

    for (int j = 0; j < 64; ++j) {
        float p0 = 0.f, p1 = 0.f, p2 = 0.f, p3 = 0.f;
#pragma unroll
        for (int k = 0; k < 16; ++k) {
            float4 w = *(const float4*)&sWgT[j * 64 + k * 4];
            p0 = fmaf(xr[k * 4 + 0], w.x, p0);
            p1 = fmaf(xr[k * 4 + 1], w.y, p1);
            p2 = fmaf(xr[k * 4 + 2], w.z, p2);
            p3 = fmaf(xr[k * 4 + 3], w.w, p3);
        }
        float acc = sbg[j] + ((p0 + p1) + (p2 + p3));
        float y = (acc >= 0.f) ? acc : NEG_SLOPE * acc;
#pragma unroll
        for (int k = 0; k < 16; ++k) {
            float4 w = *(const float4*)&sWm[j * 64 + k * 4];
            z[k * 4 + 0] = fmaf(y, w.x, z[k * 4 + 0]);
            z[k * 4 + 1] = fmaf(y, w.y, z[k * 4 + 1]);
            z[k * 4 + 2] = fmaf(y, w.z, z[k * 4 + 2]);
            z[k * 4 + 3] = fmaf(y, w.w, z[k * 4 + 3]);
        }
    }
    float nrm2 = 0.f;
#pragma unroll
    for (int j = 0; j < 64; ++j) nrm2 = fmaf(z[j], z[j], nrm2);
    float nrm = sqrtf(nrm2);
    float rn = 1.f / fmaxf(nrm, 1e-12f);
    rnorm[r] = rn;
    float4* op = (float4*)(out + (size_t)r * 64);
#pragma unroll
    for (int i = 0; i < 16; ++i) {
        float4 t;
        t.x = z[i * 4 + 0];
        t.y = z[i * 4 + 1];
        t.z = z[i * 4 + 2];
        t.w = z[i * 4 + 3];
        op[i] = t;
    }
    if (WRITE_BF) {
        uint4* bp = (uint4*)(out_bf + (size_t)r * 64);
#pragma unroll
        for (int t = 0; t < 8; ++t) {
            union { unsigned short us[8]; uint4 v; } o;
#pragma unroll
            for (int q = 0; q < 8; ++q) o.us[q] = f2bf(z[t * 8 + q]);
            bp[t] = o.v;
        }
    }
}

// ---------------- BPR scoring: grid-stride waves, 2 atomics/block ----------------
#define SCORE_BLOCKS 128
__global__ __launch_bounds__(256) void k_score(const int* __restrict__ user,
                                               const int* __restrict__ posi,
                                               const int* __restrict__ negi,
                                               const float* __restrict__ uemb,
                                               const float* __restrict__ iemb,
                                               const float* __restrict__ ego1,
                                               const float* __restrict__ rn1,
                                               const float* __restrict__ ego2,
                                               const float* __restrict__ rn2,
                                               float* __restrict__ out) {
    __shared__ float ssp[4], srg[4];
    int tid = threadIdx.x;
    int lane = tid & 63;
    int wv = tid >> 6;
    int gw = blockIdx.x * 4 + wv;
    const int NW = SCORE_BLOCKS * 4;

    float sp_acc = 0.f, rg_acc = 0.f;
    for (int w = gw; w < B_CNT; w += NW) {
        int iu = user[w], ip = posi[w], ineg = negi[w];
        size_t ru = (size_t)iu;
        size_t rp = (size_t)U_CNT + ip;
        size_t rn_ = (size_t)U_CNT + ineg;

        float u0 = uemb[(size_t)iu * 64 + lane];
        float p0 = iemb[(size_t)ip * 64 + lane];
        float n0 = iemb[(size_t)ineg * 64 + lane];
        float pos = u0 * p0;
        float neg = u0 * n0;
        float reg = u0 * u0 + p0 * p0 + n0 * n0;

        float a1 = rn1[ru], b1 = rn1[rp], c1 = rn1[rn_];
        float u1 = ego1[ru * 64 + lane] * a1;
        float p1 = ego1[rp * 64 + lane] * b1;
        float n1 = ego1[rn_ * 64 + lane] * c1;
        pos = fmaf(u1, p1, pos);
        neg = fmaf(u1, n1, neg);

        float a2 = rn2[ru], b2 = rn2[rp], c2 = rn2[rn_];
        float u2 = ego2[ru * 64 + lane] * a2;
        float p2 = ego2[rp * 64 + lane] * b2;
        float n2 = ego2[rn_ * 64 + lane] * c2;
        pos = fmaf(u2, p2, pos);
        neg = fmaf(u2, n2, neg);

#pragma unroll
        for (int off = 32; off; off >>= 1) {
            pos += __shfl_xor(pos, off);
            neg += __shfl_xor(neg, off);
            reg += __shfl_xor(reg, off);
        }
        float t = neg - pos;
        float sp = fmaxf(t, 0.f) + log1pf(expf(-fabsf(t)));
        sp_acc += sp;
        rg_acc += reg;
    }
    if (lane == 0) {
        ssp[wv] = sp_acc;
        srg[wv] = rg_acc;
    }
    __syncthreads();
    if (tid == 0) {
        float s = ssp[0] + ssp[1] + ssp[2] + ssp[3];
        float r = srg[0] + srg[1] + srg[2] + srg[3];
        atomicAdd(&out[0], s * (1.0f / B_CNT));
        atomicAdd(&out[1], r * (0.5f * REG_LAMBDA / B_CNT));
    }
}

// ---------------- launch ----------------

static inline size_t alignup(size_t x) { return (x + 255) & ~(size_t)255; }

extern "C" void kernel_launch(void* const* d_in, const int* in_sizes, int n_in,
                              void* d_out, int out_size, void* d_ws, size_t ws_size,
                              hipStream_t stream) {
    const int* user = (const int*)d_in[0];
    const int* posi = (const int*)d_in[1];
    const int* negi = (const int*)d_in[2];
    const int* rows = (const int*)d_in[3];
    const int* cols = (const int*)d_in[4];
    const float* vals = (const float*)d_in[5];
    const float* uemb = (const float*)d_in[6];
    const float* iemb = (const float*)d_in[7];
    const float* Wg0 = (const float*)d_in[8];
    const float* bg0 = (const float*)d_in[9];
    const float* Wm0 = (const float*)d_in[10];
    const float* bm0 = (const float*)d_in[11];
    const float* Wg1 = (const float*)d_in[12];
    const float* bg1 = (const float*)d_in[13];
    const float* Wm1 = (const float*)d_in[14];
    const float* bm1 = (const float*)d_in[15];
    const int E = in_sizes[3];
    float* out = (float*)d_out;

    char* p = (char*)d_ws;
    auto take = [&](size_t bytes) -> char* {
        char* q = p;
        p += alignup(bytes);
        return q;
    };
    int* rs = (int*)take((size_t)(N_CNT + 1) * 4);
    int* bcnt = (int*)take((size_t)NBK * 4 * 2);
    int* bfill = bcnt + NBK;
    int* bb = (int*)take((size_t)(NBK + 1) * 4);
    int2* edges = (int2*)take((size_t)E * 8);
    unsigned short* ego0_bf = (unsigned short*)take((size_t)N_CNT * 64 * 2);
    unsigned short* side_bf = (unsigned short*)take((size_t)N_CNT * 64 * 2);
    unsigned short* ego1_bf = (unsigned short*)take((size_t)N_CNT * 64 * 2);
    float* ego1 = (float*)take((size_t)N_CNT * 64 * 4);
    float* ego2 = (float*)take((size_t)N_CNT * 64 * 4);
    float* rn1 = (float*)take((size_t)N_CNT * 4);
    float* rn2 = (float*)take((size_t)N_CNT * 4);

    hipMemsetAsync(out, 0, 2 * sizeof(float), stream);
    hipMemsetAsync(bcnt, 0, (size_t)NBK * 4 * 2, stream);

    const long long TOT = (long long)N_CNT * 64;
    int cb = (int)((TOT / 8 + 255) / 256);
    k_cvt<<<cb, 256, 0, stream>>>(uemb, iemb, ego0_bf);

    k_bhist<<<256, 256, 0, stream>>>(rows, bcnt, E);
    k_bscan<<<1, 256, 0, stream>>>(bcnt, bb, NBK);
    k_bscatterA<<<256, 256, 0, stream>>>(rows, cols, vals, bb, bfill, edges, E);
    k_bfinal<<<NBK, 256, 0, stream>>>(edges, bb, rs, E);

    int sb = (N_CNT * 64 + 255) / 256;
    int db = (N_CNT + 255) / 256;

    k_spmm<<<sb, 256, 0, stream>>>(rs, edges, ego0_bf, side_bf);
    k_dense<1><<<db, 256, 0, stream>>>(side_bf, Wg0, bg0, Wm0, bm0, ego1, ego1_bf, rn1);
    k_spmm<<<sb, 256, 0, stream>>>(rs, edges, ego1_bf, side_bf);
    k_dense<0><<<db, 256, 0, stream>>>(side_bf, Wg1, bg1, Wm1, bm1, ego2, (unsigned short*)nullptr, rn2);

    k_score<<<SCORE_BLOCKS, 256, 0, stream>>>(user, posi, negi, uemb, iemb,
                                              ego1, rn1, ego2, rn2, out);
}

// Round 8
// 566.548 us; speedup vs baseline: 4.6792x; 1.0862x over previous
//
#include <hip/hip_runtime.h>
#include <math.h>

#define U_CNT 100000
#define I_CNT 50000
#define D_DIM 64
#define N_CNT 150000
#define B_CNT 8192
#define NEG_SLOPE 0.2f
#define REG_LAMBDA 1e-4f

#define RPB 128
#define NBK ((N_CNT + RPB - 1) / RPB)   // 1172
#define CAPB 3072                        // fixed bucket capacity (mean 2560, 10 sigma)

__device__ __forceinline__ float bf2f(unsigned short u) {
    return __uint_as_float((unsigned int)u << 16);
}
__device__ __forceinline__ unsigned short f2bf(float f) {
    unsigned int x = __float_as_uint(f);
    x += 0x7FFFu + ((x >> 16) & 1u);   // RNE
    return (unsigned short)(x >> 16);
}

// ---------------- bf16 conversion of concat(uemb, iemb) -> [N][64] ----------------
__global__ __launch_bounds__(256) void k_cvt(const float* __restrict__ uemb,
                                             const float* __restrict__ iemb,
                                             unsigned short* __restrict__ dst) {
    long long i = (long long)blockIdx.x * 256 + threadIdx.x;
    long long base = i * 8;
    const long long TOT = (long long)N_CNT * 64;
    if (base >= TOT) return;
    const long long USZ = (long long)U_CNT * 64;
    const float* s = (base < USZ) ? uemb + base : iemb + (base - USZ);
    float4 a = *(const float4*)s;
    float4 b = *(const float4*)(s + 4);
    union { unsigned short us[8]; uint4 v; } o;
    o.us[0] = f2bf(a.x); o.us[1] = f2bf(a.y); o.us[2] = f2bf(a.z); o.us[3] = f2bf(a.w);
    o.us[4] = f2bf(b.x); o.us[5] = f2bf(b.y); o.us[6] = f2bf(b.z); o.us[7] = f2bf(b.w);
    *(uint4*)(dst + base) = o.v;
}

// ---------------- single-pass bucketed scatter (fixed-capacity buckets) ----------------
// edges layout: bucket b owns [b*CAPB, b*CAPB + bfill[b])
__global__ __launch_bounds__(256) void k_bscatter(const int* __restrict__ rows,
                                                  const int* __restrict__ cols,
                                                  const float* __restrict__ vals,
                                                  int* __restrict__ bfill,
                                                  int2* __restrict__ edges, int E) {
    __shared__ int h[NBK];  // pass1: block hist; then block's base within bucket
    __shared__ int f[NBK];  // pass2 fill
    for (int i = threadIdx.x; i < NBK; i += 256) { h[i] = 0; f[i] = 0; }
    __syncthreads();
    int per = (E + gridDim.x - 1) / gridDim.x;
    int s = blockIdx.x * per, e = min(E, s + per);

    // pass 1: histogram with 8-way ILP
    int i = s + threadIdx.x;
    for (; i + 7 * 256 < e; i += 8 * 256) {
        int r[8];
#pragma unroll
        for (int j = 0; j < 8; ++j) r[j] = rows[i + j * 256];
#pragma unroll
        for (int j = 0; j < 8; ++j) atomicAdd(&h[r[j] >> 7], 1);
    }
    for (; i < e; i += 256) atomicAdd(&h[rows[i] >> 7], 1);
    __syncthreads();

    // reserve per-bucket ranges
    for (int b = threadIdx.x; b < NBK; b += 256) {
        int c = h[b];
        h[b] = c ? atomicAdd(&bfill[b], c) : 0;
    }
    __syncthreads();

    // pass 2: scatter with 8-way ILP
    i = s + threadIdx.x;
    for (; i + 7 * 256 < e; i += 8 * 256) {
        int r[8], c[8]; float v[8];
#pragma unroll
        for (int j = 0; j < 8; ++j) r[j] = rows[i + j * 256];
#pragma unroll
        for (int j = 0; j < 8; ++j) c[j] = cols[i + j * 256];
#pragma unroll
        for (int j = 0; j < 8; ++j) v[j] = vals[i + j * 256];
#pragma unroll
        for (int j = 0; j < 8; ++j) {
            int b = r[j] >> 7;
            int pos = h[b] + atomicAdd(&f[b], 1);
            if (pos < CAPB)
                edges[(size_t)b * CAPB + pos] =
                    make_int2(((r[j] & 127) << 18) | c[j], __float_as_int(v[j]));
        }
    }
    for (; i < e; i += 256) {
        int r = rows[i];
        int b = r >> 7;
        int pos = h[b] + atomicAdd(&f[b], 1);
        if (pos < CAPB)
            edges[(size_t)b * CAPB + pos] =
                make_int2(((r & 127) << 18) | cols[i], __float_as_int(vals[i]));
    }
}

// ---------------- per-bucket exact CSR sort, writes rs/re (padded CSR) ----------------
__global__ __launch_bounds__(256) void k_bfinal(int2* __restrict__ edges,
                                                const int* __restrict__ bfill,
                                                int* __restrict__ rs, int* __restrict__ re) {
    __shared__ int2 led[CAPB];                 // 24 KB
    __shared__ int lcnt[RPB], lscan[RPB], lfill[RPB], sc[RPB];
    int b = blockIdx.x;
    int s = b * CAPB;
    int nb = min(bfill[b], CAPB);
    int tid = threadIdx.x;
    if (tid < RPB) { lcnt[tid] = 0; lfill[tid] = 0; }
    __syncthreads();
    for (int i = tid; i < nb; i += 256) {
        int2 ed = edges[s + i];
        led[i] = ed;
        atomicAdd(&lcnt[ed.x >> 18], 1);
    }
    __syncthreads();
    // parallel exclusive scan over RPB=128 counters (Hillis-Steele)
    if (tid < RPB) sc[tid] = lcnt[tid];
    __syncthreads();
    for (int off = 1; off < RPB; off <<= 1) {
        int t = (tid < RPB && tid >= off) ? sc[tid - off] : 0;
        __syncthreads();
        if (tid < RPB) sc[tid] += t;
        __syncthreads();
    }
    if (tid < RPB) {
        lscan[tid] = sc[tid] - lcnt[tid];
        int row = b * RPB + tid;
        if (row < N_CNT) {
            rs[row] = s + sc[tid] - lcnt[tid];
            re[row] = s + sc[tid];
        }
    }
    __syncthreads();
    for (int i = tid; i < nb; i += 256) {
        int2 ed = led[i];
        int rl = ed.x >> 18;
        int pos = atomicAdd(&lfill[rl], 1);
        edges[s + lscan[rl] + pos] = make_int2(ed.x & 0x3FFFF, ed.y);
    }
}

// ---------------- SPMM: wave-per-row, 4x16 quad-split lanes ----------------
__global__ __launch_bounds__(256) void k_spmm(const int* __restrict__ rs,
                                              const int* __restrict__ re,
                                              const int2* __restrict__ edges,
                                              const unsigned short* __restrict__ src,
                                              unsigned short* __restrict__ out_bf) {
    int gid = blockIdx.x * blockDim.x + threadIdx.x;
    int w = gid >> 6;
    if (w >= N_CNT) return;
    int lane = threadIdx.x & 63;
    int sub = lane >> 4;
    int sl = lane & 15;
    int s = rs[w], e = re[w];

    float a0 = 0.f, a1 = 0.f, a2 = 0.f, a3 = 0.f;

    int idx = s + sub;
    int2 cur = (idx < e) ? edges[idx] : make_int2(0, 0);
    if (idx >= e) cur.y = 0;
    for (int base = s; base < e; base += 4) {
        int nidx = base + 4 + sub;
        int2 nxt = make_int2(0, 0);
        if (nidx < e) nxt = edges[nidx];
        unsigned int col = (unsigned int)cur.x;
        uint2 g = *(const uint2*)(src + (size_t)col * 64 + sl * 4);
        float v = __int_as_float(cur.y);
        a0 = fmaf(v, __uint_as_float(g.x << 16), a0);
        a1 = fmaf(v, __uint_as_float(g.x & 0xFFFF0000u), a1);
        a2 = fmaf(v, __uint_as_float(g.y << 16), a2);
        a3 = fmaf(v, __uint_as_float(g.y & 0xFFFF0000u), a3);
        cur = nxt;
    }
    a0 += __shfl_xor(a0, 16); a0 += __shfl_xor(a0, 32);
    a1 += __shfl_xor(a1, 16); a1 += __shfl_xor(a1, 32);
    a2 += __shfl_xor(a2, 16); a2 += __shfl_xor(a2, 32);
    a3 += __shfl_xor(a3, 16); a3 += __shfl_xor(a3, 32);
    if (sub == 0) {
        union { unsigned short us[4]; uint2 u; } o;
        o.us[0] = f2bf(a0); o.us[1] = f2bf(a1);
        o.us[2] = f2bf(a2); o.us[3] = f2bf(a3);
        *(uint2*)&out_bf[(size_t)w * 64 + sl * 4] = o.u;
    }
}

// ---------------- fused dense ----------------
template <int WRITE_BF>
__global__ __launch_bounds__(256, 2) void k_dense(const unsigned short* __restrict__ x_in,
                                                  const float* __restrict__ Wg,
                                                  const float* __restrict__ bg,
                                                  const float* __restrict__ Wm,
                                                  const float* __restrict__ bm,
                                                  float* __restrict__ out,
                                                  unsigned short* __restrict__ out_bf,
                                                  float* __restrict__ rnorm) {
    __shared__ __align__(16) float sWgT[4096];
    __shared__ __align__(16) float sWm[4096];
    __shared__ float sbg[64], sbm[64];
    int tid = threadIdx.x;
    for (int i = tid; i < 4096; i += 256) {
        int k = i >> 6, j = i & 63;
        sWgT[j * 64 + k] = Wg[i];
        sWm[i] = Wm[i];
    }
    if (tid < 64) {
        sbg[tid] = bg[tid];
        sbm[tid] = bm[tid];
    }
    __syncthreads();
    int r = blockIdx.x * 256 + tid;
    if (r >= N_CNT) return;

    float xr[64];
    const uint4* xp = (const uint4*)(x_in + (size_t)r * 64);
#pragma unroll
    for (int t = 0; t < 8; ++t) {
        uint4 q = xp[t];
        unsigned int u;
        u = q.x; xr[t * 8 + 0] = __uint_as_float(u << 16); xr[t * 8 + 1] = __uint_as_float(u & 0xFFFF0000u);
        u = q.y; xr[t * 8 + 2] = __uint_as_float(u << 16); xr[t * 8 + 3] = __uint_as_float(u & 0xFFFF0000u);
        u = q.z; xr[t * 8 + 4] = __uint_as_float(u << 16); xr[t * 8 + 5] = __uint_as_float(u & 0xFFFF0000u);
        u = q.w; xr[t * 8 + 6] = __uint_as_float(u << 16); xr[t * 8 + 7] = __uint_as_float(u & 0xFFFF0000u);
    }

    float z[64];
#pragma unroll
    for (int j = 0; j < 64; ++j) z[j] = sbm[j];

    for (int j = 0; j < 64; ++j) {
        float p0 = 0.f, p1 = 0.f, p2 = 0.f, p3 = 0.f;
#pragma unroll
        for (int k = 0; k < 16; ++k) {
            float4 w = *(const float4*)&sWgT[j * 64 + k * 4];
            p0 = fmaf(xr[k * 4 + 0], w.x, p0);
            p1 = fmaf(xr[k * 4 + 1], w.y, p1);
            p2 = fmaf(xr[k * 4 + 2], w.z, p2);
            p3 = fmaf(xr[k * 4 + 3], w.w, p3);
        }
        float acc = sbg[j] + ((p0 + p1) + (p2 + p3));
        float y = (acc >= 0.f) ? acc : NEG_SLOPE * acc;
#pragma unroll
        for (int k = 0; k < 16; ++k) {
            float4 w = *(const float4*)&sWm[j * 64 + k * 4];
            z[k * 4 + 0] = fmaf(y, w.x, z[k * 4 + 0]);
            z[k * 4 + 1] = fmaf(y, w.y, z[k * 4 + 1]);
            z[k * 4 + 2] = fmaf(y, w.z, z[k * 4 + 2]);
            z[k * 4 + 3] = fmaf(y, w.w, z[k * 4 + 3]);
        }
    }
    float nrm2 = 0.f;
#pragma unroll
    for (int j = 0; j < 64; ++j) nrm2 = fmaf(z[j], z[j], nrm2);
    float nrm = sqrtf(nrm2);
    float rn = 1.f / fmaxf(nrm, 1e-12f);
    rnorm[r] = rn;
    float4* op = (float4*)(out + (size_t)r * 64);
#pragma unroll
    for (int i = 0; i < 16; ++i) {
        float4 t;
        t.x = z[i * 4 + 0];
        t.y = z[i * 4 + 1];
        t.z = z[i * 4 + 2];
        t.w = z[i * 4 + 3];
        op[i] = t;
    }
    if (WRITE_BF) {
        uint4* bp = (uint4*)(out_bf + (size_t)r * 64);
#pragma unroll
        for (int t = 0; t < 8; ++t) {
            union { unsigned short us[8]; uint4 v; } o;
#pragma unroll
            for (int q = 0; q < 8; ++q) o.us[q] = f2bf(z[t * 8 + q]);
            bp[t] = o.v;
        }
    }
}

// ---------------- BPR scoring: grid-stride waves, 2 atomics/block ----------------
#define SCORE_BLOCKS 128
__global__ __launch_bounds__(256) void k_score(const int* __restrict__ user,
                                               const int* __restrict__ posi,
                                               const int* __restrict__ negi,
                                               const float* __restrict__ uemb,
                                               const float* __restrict__ iemb,
                                               const float* __restrict__ ego1,
                                               const float* __restrict__ rn1,
                                               const float* __restrict__ ego2,
                                               const float* __restrict__ rn2,
                                               float* __restrict__ out) {
    __shared__ float ssp[4], srg[4];
    int tid = threadIdx.x;
    int lane = tid & 63;
    int wv = tid >> 6;
    int gw = blockIdx.x * 4 + wv;
    const int NW = SCORE_BLOCKS * 4;

    float sp_acc = 0.f, rg_acc = 0.f;
    for (int w = gw; w < B_CNT; w += NW) {
        int iu = user[w], ip = posi[w], ineg = negi[w];
        size_t ru = (size_t)iu;
        size_t rp = (size_t)U_CNT + ip;
        size_t rn_ = (size_t)U_CNT + ineg;

        float u0 = uemb[(size_t)iu * 64 + lane];
        float p0 = iemb[(size_t)ip * 64 + lane];
        float n0 = iemb[(size_t)ineg * 64 + lane];
        float pos = u0 * p0;
        float neg = u0 * n0;
        float reg = u0 * u0 + p0 * p0 + n0 * n0;

        float a1 = rn1[ru], b1 = rn1[rp], c1 = rn1[rn_];
        float u1 = ego1[ru * 64 + lane] * a1;
        float p1 = ego1[rp * 64 + lane] * b1;
        float n1 = ego1[rn_ * 64 + lane] * c1;
        pos = fmaf(u1, p1, pos);
        neg = fmaf(u1, n1, neg);

        float a2 = rn2[ru], b2 = rn2[rp], c2 = rn2[rn_];
        float u2 = ego2[ru * 64 + lane] * a2;
        float p2 = ego2[rp * 64 + lane] * b2;
        float n2 = ego2[rn_ * 64 + lane] * c2;
        pos = fmaf(u2, p2, pos);
        neg = fmaf(u2, n2, neg);

#pragma unroll
        for (int off = 32; off; off >>= 1) {
            pos += __shfl_xor(pos, off);
            neg += __shfl_xor(neg, off);
            reg += __shfl_xor(reg, off);
        }
        float t = neg - pos;
        float sp = fmaxf(t, 0.f) + log1pf(expf(-fabsf(t)));
        sp_acc += sp;
        rg_acc += reg;
    }
    if (lane == 0) {
        ssp[wv] = sp_acc;
        srg[wv] = rg_acc;
    }
    __syncthreads();
    if (tid == 0) {
        float s = ssp[0] + ssp[1] + ssp[2] + ssp[3];
        float r = srg[0] + srg[1] + srg[2] + srg[3];
        atomicAdd(&out[0], s * (1.0f / B_CNT));
        atomicAdd(&out[1], r * (0.5f * REG_LAMBDA / B_CNT));
    }
}

// ---------------- launch ----------------

static inline size_t alignup(size_t x) { return (x + 255) & ~(size_t)255; }

extern "C" void kernel_launch(void* const* d_in, const int* in_sizes, int n_in,
                              void* d_out, int out_size, void* d_ws, size_t ws_size,
                              hipStream_t stream) {
    const int* user = (const int*)d_in[0];
    const int* posi = (const int*)d_in[1];
    const int* negi = (const int*)d_in[2];
    const int* rows = (const int*)d_in[3];
    const int* cols = (const int*)d_in[4];
    const float* vals = (const float*)d_in[5];
    const float* uemb = (const float*)d_in[6];
    const float* iemb = (const float*)d_in[7];
    const float* Wg0 = (const float*)d_in[8];
    const float* bg0 = (const float*)d_in[9];
    const float* Wm0 = (const float*)d_in[10];
    const float* bm0 = (const float*)d_in[11];
    const float* Wg1 = (const float*)d_in[12];
    const float* bg1 = (const float*)d_in[13];
    const float* Wm1 = (const float*)d_in[14];
    const float* bm1 = (const float*)d_in[15];
    const int E = in_sizes[3];
    float* out = (float*)d_out;

    char* p = (char*)d_ws;
    auto take = [&](size_t bytes) -> char* {
        char* q = p;
        p += alignup(bytes);
        return q;
    };
    int* rs = (int*)take((size_t)N_CNT * 4);
    int* re = (int*)take((size_t)N_CNT * 4);
    int* bfill = (int*)take((size_t)NBK * 4);
    int2* edges = (int2*)take((size_t)NBK * CAPB * 8);
    unsigned short* ego0_bf = (unsigned short*)take((size_t)N_CNT * 64 * 2);
    unsigned short* side_bf = (unsigned short*)take((size_t)N_CNT * 64 * 2);
    unsigned short* ego1_bf = (unsigned short*)take((size_t)N_CNT * 64 * 2);
    float* ego1 = (float*)take((size_t)N_CNT * 64 * 4);
    float* ego2 = (float*)take((size_t)N_CNT * 64 * 4);
    float* rn1 = (float*)take((size_t)N_CNT * 4);
    float* rn2 = (float*)take((size_t)N_CNT * 4);

    hipMemsetAsync(out, 0, 2 * sizeof(float), stream);
    hipMemsetAsync(bfill, 0, (size_t)NBK * 4, stream);

    const long long TOT = (long long)N_CNT * 64;
    int cb = (int)((TOT / 8 + 255) / 256);
    k_cvt<<<cb, 256, 0, stream>>>(uemb, iemb, ego0_bf);

    k_bscatter<<<512, 256, 0, stream>>>(rows, cols, vals, bfill, edges, E);
    k_bfinal<<<NBK, 256, 0, stream>>>(edges, bfill, rs, re);

    int sb = (N_CNT * 64 + 255) / 256;
    int db = (N_CNT + 255) / 256;

    k_spmm<<<sb, 256, 0, stream>>>(rs, re, edges, ego0_bf, side_bf);
    k_dense<1><<<db, 256, 0, stream>>>(side_bf, Wg0, bg0, Wm0, bm0, ego1, ego1_bf, rn1);
    k_spmm<<<sb, 256, 0, stream>>>(rs, re, edges, ego1_bf, side_bf);
    k_dense<0><<<db, 256, 0, stream>>>(side_bf, Wg1, bg1, Wm1, bm1, ego2, (unsigned short*)nullptr, rn2);

    k_score<<<SCORE_BLOCKS, 256, 0, stream>>>(user, posi, negi, uemb, iemb,
                                              ego1, rn1, ego2, rn2, out);
}

// Round 11
// 547.653 us; speedup vs baseline: 4.8406x; 1.0345x over previous
//
#include <hip/hip_runtime.h>
#include <math.h>

#define U_CNT 100000
#define I_CNT 50000
#define D_DIM 64
#define N_CNT 150000
#define B_CNT 8192
#define NEG_SLOPE 0.2f
#define REG_LAMBDA 1e-4f

#define RPB 128
#define NBK ((N_CNT + RPB - 1) / RPB)   // 1172
#define CAPB 3072                        // fixed bucket capacity (mean 2560, 10 sigma)

__device__ __forceinline__ float bf2f(unsigned short u) {
    return __uint_as_float((unsigned int)u << 16);
}
__device__ __forceinline__ unsigned short f2bf(float f) {
    unsigned int x = __float_as_uint(f);
    x += 0x7FFFu + ((x >> 16) & 1u);   // RNE
    return (unsigned short)(x >> 16);
}

// ---------------- bf16 conversion of concat(uemb, iemb) -> [N][64] ----------------
__global__ __launch_bounds__(256) void k_cvt(const float* __restrict__ uemb,
                                             const float* __restrict__ iemb,
                                             unsigned short* __restrict__ dst) {
    long long i = (long long)blockIdx.x * 256 + threadIdx.x;
    long long base = i * 8;
    const long long TOT = (long long)N_CNT * 64;
    if (base >= TOT) return;
    const long long USZ = (long long)U_CNT * 64;
    const float* s = (base < USZ) ? uemb + base : iemb + (base - USZ);
    float4 a = *(const float4*)s;
    float4 b = *(const float4*)(s + 4);
    union { unsigned short us[8]; uint4 v; } o;
    o.us[0] = f2bf(a.x); o.us[1] = f2bf(a.y); o.us[2] = f2bf(a.z); o.us[3] = f2bf(a.w);
    o.us[4] = f2bf(b.x); o.us[5] = f2bf(b.y); o.us[6] = f2bf(b.z); o.us[7] = f2bf(b.w);
    *(uint4*)(dst + base) = o.v;
}

// ---------------- transpose 64x64 Wg matrices (tiny prep) ----------------
__global__ __launch_bounds__(256) void k_prep(const float* __restrict__ Wg0,
                                              const float* __restrict__ Wg1,
                                              float* __restrict__ WgT0,
                                              float* __restrict__ WgT1) {
    const float* src = (blockIdx.x == 0) ? Wg0 : Wg1;
    float* dst = (blockIdx.x == 0) ? WgT0 : WgT1;
    int t = threadIdx.x;
    int j = t >> 2;            // output row (0..63)
    int kb = (t & 3) * 16;     // 16 k per thread
#pragma unroll
    for (int k = 0; k < 16; ++k) {
        dst[j * 64 + kb + k] = src[(kb + k) * 64 + j];
    }
}

// ---------------- single-pass bucketed scatter (fixed-capacity buckets) ----------------
__global__ __launch_bounds__(256) void k_bscatter(const int* __restrict__ rows,
                                                  const int* __restrict__ cols,
                                                  const float* __restrict__ vals,
                                                  int* __restrict__ bfill,
                                                  int2* __restrict__ edges, int E) {
    __shared__ int h[NBK];
    __shared__ int f[NBK];
    for (int i = threadIdx.x; i < NBK; i += 256) { h[i] = 0; f[i] = 0; }
    __syncthreads();
    int per = (E + gridDim.x - 1) / gridDim.x;
    int s = blockIdx.x * per, e = min(E, s + per);

    int i = s + threadIdx.x;
    for (; i + 7 * 256 < e; i += 8 * 256) {
        int r[8];
#pragma unroll
        for (int j = 0; j < 8; ++j) r[j] = rows[i + j * 256];
#pragma unroll
        for (int j = 0; j < 8; ++j) atomicAdd(&h[r[j] >> 7], 1);
    }
    for (; i < e; i += 256) atomicAdd(&h[rows[i] >> 7], 1);
    __syncthreads();

    for (int b = threadIdx.x; b < NBK; b += 256) {
        int c = h[b];
        h[b] = c ? atomicAdd(&bfill[b], c) : 0;
    }
    __syncthreads();

    i = s + threadIdx.x;
    for (; i + 7 * 256 < e; i += 8 * 256) {
        int r[8], c[8]; float v[8];
#pragma unroll
        for (int j = 0; j < 8; ++j) r[j] = rows[i + j * 256];
#pragma unroll
        for (int j = 0; j < 8; ++j) c[j] = cols[i + j * 256];
#pragma unroll
        for (int j = 0; j < 8; ++j) v[j] = vals[i + j * 256];
#pragma unroll
        for (int j = 0; j < 8; ++j) {
            int b = r[j] >> 7;
            int pos = h[b] + atomicAdd(&f[b], 1);
            if (pos < CAPB)
                edges[(size_t)b * CAPB + pos] =
                    make_int2(((r[j] & 127) << 18) | c[j], __float_as_int(v[j]));
        }
    }
    for (; i < e; i += 256) {
        int r = rows[i];
        int b = r >> 7;
        int pos = h[b] + atomicAdd(&f[b], 1);
        if (pos < CAPB)
            edges[(size_t)b * CAPB + pos] =
                make_int2(((r & 127) << 18) | cols[i], __float_as_int(vals[i]));
    }
}

// ---------------- per-bucket exact CSR sort, writes rs/re (padded CSR) ----------------
__global__ __launch_bounds__(256) void k_bfinal(int2* __restrict__ edges,
                                                const int* __restrict__ bfill,
                                                int* __restrict__ rs, int* __restrict__ re) {
    __shared__ int2 led[CAPB];                 // 24 KB
    __shared__ int lcnt[RPB], lscan[RPB], lfill[RPB], sc[RPB];
    int b = blockIdx.x;
    int s = b * CAPB;
    int nb = min(bfill[b], CAPB);
    int tid = threadIdx.x;
    if (tid < RPB) { lcnt[tid] = 0; lfill[tid] = 0; }
    __syncthreads();
    for (int i = tid; i < nb; i += 256) {
        int2 ed = edges[s + i];
        led[i] = ed;
        atomicAdd(&lcnt[ed.x >> 18], 1);
    }
    __syncthreads();
    if (tid < RPB) sc[tid] = lcnt[tid];
    __syncthreads();
    for (int off = 1; off < RPB; off <<= 1) {
        int t = (tid < RPB && tid >= off) ? sc[tid - off] : 0;
        __syncthreads();
        if (tid < RPB) sc[tid] += t;
        __syncthreads();
    }
    if (tid < RPB) {
        lscan[tid] = sc[tid] - lcnt[tid];
        int row = b * RPB + tid;
        if (row < N_CNT) {
            rs[row] = s + sc[tid] - lcnt[tid];
            re[row] = s + sc[tid];
        }
    }
    __syncthreads();
    for (int i = tid; i < nb; i += 256) {
        int2 ed = led[i];
        int rl = ed.x >> 18;
        int pos = atomicAdd(&lfill[rl], 1);
        edges[s + lscan[rl] + pos] = make_int2(ed.x & 0x3FFFF, ed.y);
    }
}

// ---------------- SPMM: wave-per-row, 4x16 quad-split lanes ----------------
__global__ __launch_bounds__(256) void k_spmm(const int* __restrict__ rs,
                                              const int* __restrict__ re,
                                              const int2* __restrict__ edges,
                                              const unsigned short* __restrict__ src,
                                              unsigned short* __restrict__ out_bf) {
    int gid = blockIdx.x * blockDim.x + threadIdx.x;
    int w = gid >> 6;
    if (w >= N_CNT) return;
    int lane = threadIdx.x & 63;
    int sub = lane >> 4;
    int sl = lane & 15;
    int s = rs[w], e = re[w];

    float a0 = 0.f, a1 = 0.f, a2 = 0.f, a3 = 0.f;

    int idx = s + sub;
    int2 cur = (idx < e) ? edges[idx] : make_int2(0, 0);
    if (idx >= e) cur.y = 0;
    for (int base = s; base < e; base += 4) {
        int nidx = base + 4 + sub;
        int2 nxt = make_int2(0, 0);
        if (nidx < e) nxt = edges[nidx];
        unsigned int col = (unsigned int)cur.x;
        uint2 g = *(const uint2*)(src + (size_t)col * 64 + sl * 4);
        float v = __int_as_float(cur.y);
        a0 = fmaf(v, __uint_as_float(g.x << 16), a0);
        a1 = fmaf(v, __uint_as_float(g.x & 0xFFFF0000u), a1);
        a2 = fmaf(v, __uint_as_float(g.y << 16), a2);
        a3 = fmaf(v, __uint_as_float(g.y & 0xFFFF0000u), a3);
        cur = nxt;
    }
    a0 += __shfl_xor(a0, 16); a0 += __shfl_xor(a0, 32);
    a1 += __shfl_xor(a1, 16); a1 += __shfl_xor(a1, 32);
    a2 += __shfl_xor(a2, 16); a2 += __shfl_xor(a2, 32);
    a3 += __shfl_xor(a3, 16); a3 += __shfl_xor(a3, 32);
    if (sub == 0) {
        union { unsigned short us[4]; uint2 u; } o;
        o.us[0] = f2bf(a0); o.us[1] = f2bf(a1);
        o.us[2] = f2bf(a2); o.us[3] = f2bf(a3);
        *(uint2*)&out_bf[(size_t)w * 64 + sl * 4] = o.u;
    }
}

// ---------------- fused dense: weights via wave-uniform scalar loads ----------------
template <int WRITE_BF>
__global__ __launch_bounds__(256) void k_dense(const unsigned short* __restrict__ x_in,
                                               const float* __restrict__ WgT,
                                               const float* __restrict__ bg,
                                               const float* __restrict__ Wm,
                                               const float* __restrict__ bm,
                                               float* __restrict__ out,
                                               unsigned short* __restrict__ out_bf,
                                               float* __restrict__ rnorm) {
    int tid = threadIdx.x;
    int r = blockIdx.x * 256 + tid;
    if (r >= N_CNT) return;

    float xr[64];
    const uint4* xp = (const uint4*)(x_in + (size_t)r * 64);
#pragma unroll
    for (int t = 0; t < 8; ++t) {
        uint4 q = xp[t];
        unsigned int u;
        u = q.x; xr[t * 8 + 0] = __uint_as_float(u << 16); xr[t * 8 + 1] = __uint_as_float(u & 0xFFFF0000u);
        u = q.y; xr[t * 8 + 2] = __uint_as_float(u << 16); xr[t * 8 + 3] = __uint_as_float(u & 0xFFFF0000u);
        u = q.z; xr[t * 8 + 4] = __uint_as_float(u << 16); xr[t * 8 + 5] = __uint_as_float(u & 0xFFFF0000u);
        u = q.w; xr[t * 8 + 6] = __uint_as_float(u << 16); xr[t * 8 + 7] = __uint_as_float(u & 0xFFFF0000u);
    }

    float z[64];
#pragma unroll
    for (int j = 0; j < 64; ++j) z[j] = bm[j];   // uniform -> scalar load

#pragma unroll 2
    for (int j = 0; j < 64; ++j) {
        const float* wg = WgT + j * 64;          // uniform base
        float p0 = 0.f, p1 = 0.f, p2 = 0.f, p3 = 0.f;
#pragma unroll
        for (int k = 0; k < 16; ++k) {
            p0 = fmaf(xr[k * 4 + 0], wg[k * 4 + 0], p0);
            p1 = fmaf(xr[k * 4 + 1], wg[k * 4 + 1], p1);
            p2 = fmaf(xr[k * 4 + 2], wg[k * 4 + 2], p2);
            p3 = fmaf(xr[k * 4 + 3], wg[k * 4 + 3], p3);
        }
        float acc = bg[j] + ((p0 + p1) + (p2 + p3));
        float y = (acc >= 0.f) ? acc : NEG_SLOPE * acc;
        const float* wm = Wm + j * 64;           // uniform base
#pragma unroll
        for (int k = 0; k < 16; ++k) {
            z[k * 4 + 0] = fmaf(y, wm[k * 4 + 0], z[k * 4 + 0]);
            z[k * 4 + 1] = fmaf(y, wm[k * 4 + 1], z[k * 4 + 1]);
            z[k * 4 + 2] = fmaf(y, wm[k * 4 + 2], z[k * 4 + 2]);
            z[k * 4 + 3] = fmaf(y, wm[k * 4 + 3], z[k * 4 + 3]);
        }
    }
    float nrm2 = 0.f;
#pragma unroll
    for (int j = 0; j < 64; ++j) nrm2 = fmaf(z[j], z[j], nrm2);
    float nrm = sqrtf(nrm2);
    float rn = 1.f / fmaxf(nrm, 1e-12f);
    rnorm[r] = rn;
    float4* op = (float4*)(out + (size_t)r * 64);
#pragma unroll
    for (int i = 0; i < 16; ++i) {
        float4 t;
        t.x = z[i * 4 + 0];
        t.y = z[i * 4 + 1];
        t.z = z[i * 4 + 2];
        t.w = z[i * 4 + 3];
        op[i] = t;
    }
    if (WRITE_BF) {
        uint4* bp = (uint4*)(out_bf + (size_t)r * 64);
#pragma unroll
        for (int t = 0; t < 8; ++t) {
            union { unsigned short us[8]; uint4 v; } o;
#pragma unroll
            for (int q = 0; q < 8; ++q) o.us[q] = f2bf(z[t * 8 + q]);
            bp[t] = o.v;
        }
    }
}

// ---------------- BPR scoring: grid-stride waves, 2 atomics/block ----------------
#define SCORE_BLOCKS 128
__global__ __launch_bounds__(256) void k_score(const int* __restrict__ user,
                                               const int* __restrict__ posi,
                                               const int* __restrict__ negi,
                                               const float* __restrict__ uemb,
                                               const float* __restrict__ iemb,
                                               const float* __restrict__ ego1,
                                               const float* __restrict__ rn1,
                                               const float* __restrict__ ego2,
                                               const float* __restrict__ rn2,
                                               float* __restrict__ out) {
    __shared__ float ssp[4], srg[4];
    int tid = threadIdx.x;
    int lane = tid & 63;
    int wv = tid >> 6;
    int gw = blockIdx.x * 4 + wv;
    const int NW = SCORE_BLOCKS * 4;

    float sp_acc = 0.f, rg_acc = 0.f;
    for (int w = gw; w < B_CNT; w += NW) {
        int iu = user[w], ip = posi[w], ineg = negi[w];
        size_t ru = (size_t)iu;
        size_t rp = (size_t)U_CNT + ip;
        size_t rn_ = (size_t)U_CNT + ineg;

        float u0 = uemb[(size_t)iu * 64 + lane];
        float p0 = iemb[(size_t)ip * 64 + lane];
        float n0 = iemb[(size_t)ineg * 64 + lane];
        float pos = u0 * p0;
        float neg = u0 * n0;
        float reg = u0 * u0 + p0 * p0 + n0 * n0;

        float a1 = rn1[ru], b1 = rn1[rp], c1 = rn1[rn_];
        float u1 = ego1[ru * 64 + lane] * a1;
        float p1 = ego1[rp * 64 + lane] * b1;
        float n1 = ego1[rn_ * 64 + lane] * c1;
        pos = fmaf(u1, p1, pos);
        neg = fmaf(u1, n1, neg);

        float a2 = rn2[ru], b2 = rn2[rp], c2 = rn2[rn_];
        float u2 = ego2[ru * 64 + lane] * a2;
        float p2 = ego2[rp * 64 + lane] * b2;
        float n2 = ego2[rn_ * 64 + lane] * c2;
        pos = fmaf(u2, p2, pos);
        neg = fmaf(u2, n2, neg);

#pragma unroll
        for (int off = 32; off; off >>= 1) {
            pos += __shfl_xor(pos, off);
            neg += __shfl_xor(neg, off);
            reg += __shfl_xor(reg, off);
        }
        float t = neg - pos;
        float sp = fmaxf(t, 0.f) + log1pf(expf(-fabsf(t)));
        sp_acc += sp;
        rg_acc += reg;
    }
    if (lane == 0) {
        ssp[wv] = sp_acc;
        srg[wv] = rg_acc;
    }
    __syncthreads();
    if (tid == 0) {
        float s = ssp[0] + ssp[1] + ssp[2] + ssp[3];
        float r = srg[0] + srg[1] + srg[2] + srg[3];
        atomicAdd(&out[0], s * (1.0f / B_CNT));
        atomicAdd(&out[1], r * (0.5f * REG_LAMBDA / B_CNT));
    }
}

// ---------------- launch ----------------

static inline size_t alignup(size_t x) { return (x + 255) & ~(size_t)255; }

extern "C" void kernel_launch(void* const* d_in, const int* in_sizes, int n_in,
                              void* d_out, int out_size, void* d_ws, size_t ws_size,
                              hipStream_t stream) {
    const int* user = (const int*)d_in[0];
    const int* posi = (const int*)d_in[1];
    const int* negi = (const int*)d_in[2];
    const int* rows = (const int*)d_in[3];
    const int* cols = (const int*)d_in[4];
    const float* vals = (const float*)d_in[5];
    const float* uemb = (const float*)d_in[6];
    const float* iemb = (const float*)d_in[7];
    const float* Wg0 = (const float*)d_in[8];
    const float* bg0 = (const float*)d_in[9];
    const float* Wm0 = (const float*)d_in[10];
    const float* bm0 = (const float*)d_in[11];
    const float* Wg1 = (const float*)d_in[12];
    const float* bg1 = (const float*)d_in[13];
    const float* Wm1 = (const float*)d_in[14];
    const float* bm1 = (const float*)d_in[15];
    const int E = in_sizes[3];
    float* out = (float*)d_out;

    char* p = (char*)d_ws;
    auto take = [&](size_t bytes) -> char* {
        char* q = p;
        p += alignup(bytes);
        return q;
    };
    int* rs = (int*)take((size_t)N_CNT * 4);
    int* re = (int*)take((size_t)N_CNT * 4);
    int* bfill = (int*)take((size_t)NBK * 4);
    float* wgt0 = (float*)take(4096 * 4);
    float* wgt1 = (float*)take(4096 * 4);
    int2* edges = (int2*)take((size_t)NBK * CAPB * 8);
    unsigned short* ego0_bf = (unsigned short*)take((size_t)N_CNT * 64 * 2);
    unsigned short* side_bf = (unsigned short*)take((size_t)N_CNT * 64 * 2);
    unsigned short* ego1_bf = (unsigned short*)take((size_t)N_CNT * 64 * 2);
    float* ego1 = (float*)take((size_t)N_CNT * 64 * 4);
    float* ego2 = (float*)take((size_t)N_CNT * 64 * 4);
    float* rn1 = (float*)take((size_t)N_CNT * 4);
    float* rn2 = (float*)take((size_t)N_CNT * 4);

    hipMemsetAsync(out, 0, 2 * sizeof(float), stream);
    hipMemsetAsync(bfill, 0, (size_t)NBK * 4, stream);

    const long long TOT = (long long)N_CNT * 64;
    int cb = (int)((TOT / 8 + 255) / 256);
    k_cvt<<<cb, 256, 0, stream>>>(uemb, iemb, ego0_bf);
    k_prep<<<2, 256, 0, stream>>>(Wg0, Wg1, wgt0, wgt1);

    k_bscatter<<<512, 256, 0, stream>>>(rows, cols, vals, bfill, edges, E);
    k_bfinal<<<NBK, 256, 0, stream>>>(edges, bfill, rs, re);

    int sb = (N_CNT * 64 + 255) / 256;
    int db = (N_CNT + 255) / 256;

    k_spmm<<<sb, 256, 0, stream>>>(rs, re, edges, ego0_bf, side_bf);
    k_dense<1><<<db, 256, 0, stream>>>(side_bf, wgt0, bg0, Wm0, bm0, ego1, ego1_bf, rn1);
    k_spmm<<<sb, 256, 0, stream>>>(rs, re, edges, ego1_bf, side_bf);
    k_dense<0><<<db, 256, 0, stream>>>(side_bf, wgt1, bg1, Wm1, bm1, ego2, (unsigned short*)nullptr, rn2);

    k_score<<<SCORE_BLOCKS, 256, 0, stream>>>(user, posi, negi, uemb, iemb,
                                              ego1, rn1, ego2, rn2, out);
}